// Round 15
// baseline (4362.080 us; speedup 1.0000x reference)
//
#include <hip/hip_runtime.h>
#include <hip/hip_bf16.h>
#include <math.h>

using bf16 = __hip_bfloat16;
typedef __bf16 bf16x8 __attribute__((ext_vector_type(8)));
typedef float f32x4 __attribute__((ext_vector_type(4)));

// Problem dims
static constexpr int NB = 512, NH = 1024, NOH = 4096, NC = 512, NT = 40;
static constexpr int SPLITK = 4;

// All LDS-staged matrices are "chunk-swizzled": element (r,k) stored at
// r*K + (k ^ ((r&7)<<3)) (within each 64-elem k-window).  global_load_lds
// copies rows linearly (swizzle-preserving); fragment reads XOR the byte
// address with ((l15&7)<<4), spreading 16 fragment rows over 8 bank groups.

// ---------------------------------------------------------------------------
// Transpose-cast fp32 (K x N) -> bf16 (N x K), chunk-swizzled.
// ---------------------------------------------------------------------------
__global__ void transpose_cast(const float* __restrict__ W, bf16* __restrict__ WT,
                               int K, int N) {
  __shared__ float tile[32][33];
  const int n0 = blockIdx.x * 32;
  const int k0 = blockIdx.y * 32;
  const int tx = threadIdx.x;
  const int ty = threadIdx.y;
#pragma unroll
  for (int i = 0; i < 4; ++i) {
    int r = ty + i * 8;
    tile[r][tx] = W[(size_t)(k0 + r) * N + n0 + tx];
  }
  __syncthreads();
#pragma unroll
  for (int i = 0; i < 4; ++i) {
    int r = ty + i * 8;
    const int n = n0 + r, k = k0 + tx;
    WT[(size_t)n * K + (k ^ ((n & 7) << 3))] = __float2bfloat16(tile[tx][r]);
  }
}

// ---------------------------------------------------------------------------
// Init: y = z (fp32), yb = pred[0] = bf16(z) (chunk-swizzled).
// ---------------------------------------------------------------------------
__global__ void init_state(const float* __restrict__ z, float* __restrict__ y,
                           bf16* __restrict__ yb, bf16* __restrict__ pred0) {
  const int i = blockIdx.x * 256 + threadIdx.x;
  const int r = i >> 10, c = i & (NH - 1);
  float v = z[i];
  y[i] = v;
  bf16 b = __float2bfloat16(v);
  const int sw = r * NH + (c ^ ((r & 7) << 3));
  yb[sw] = b;
  pred0[sw] = b;
}

// ---------------------------------------------------------------------------
// Stage GEMM: 64x128 tile, BK=128, K-chunk=1024 (8 iters), 4 waves (2x2:
// per-wave 32x64 output).  2 dyn-LDS buffers (96 KB -> 1 block/CU), counted-
// vmcnt pipeline (R14-proven): per iter
//   s_barrier -> issue group j+1 (12 loads) -> vmcnt(12) -> compute (32 MFMA)
// Per-iter ds_read:MFMA improves to 24:32 (was 16:16); A-side L2 traffic
// halves vs 64x64 tiles; WG count halves; barrier count unchanged.
// XCD-aware decode: xcd = bid&7 -> each XCD's weight slice = 1MB, L2-resident.
// EPI 0 (GEMM1): h = bf16(tanh(acc + b1[col]))   [512x4096], swizzled store
// EPI 1 (GEMM2): part[kz] = acc (fp32 partials)  [4 x 512x1024]
// ---------------------------------------------------------------------------
template <int EPI>
__global__ __launch_bounds__(256, 1) void gemm_stage(
    const bf16* __restrict__ A, const bf16* __restrict__ BT,
    const float* __restrict__ bias, bf16* __restrict__ outB,
    float* __restrict__ outF) {
  constexpr int BK = 128;
  constexpr int KCH = 1024;
  constexpr int KST = (EPI == 0) ? NH : NOH;   // operand row stride
  constexpr int NOUT = (EPI == 0) ? NOH : NH;  // output row stride
  constexpr int NI = KCH / BK;                 // 8 K-iterations

  extern __shared__ __align__(16) char smem[];
  // A bufs: 2 x 16 KB at [0, 32KB); B bufs: 2 x 32 KB at [32KB, 96KB)
  char* AsB = smem;
  char* BsB = smem + 32768;

  const int tid = threadIdx.x;
  const int lane = tid & 63;
  const int wave = tid >> 6;
  const int wr = wave >> 1, wc = wave & 1;
  const int l15 = lane & 15, kg = lane >> 4;
  const int xorB = (l15 & 7) << 4;
  const int srow = tid >> 4;        // staging row within 16-row round
  const int scol = (tid & 15) * 8;  // staging elem offset (128-elem rows)

  // XCD-aware task decode (blockIdx % 8 -> XCD round-robin).  Grid 256.
  const int bid = blockIdx.x;
  const int xcd = bid & 7, slot = bid >> 3;  // slot 0..31
  int row0, col0, kbeg;
  float* outFb = outF;
  if constexpr (EPI == 0) {
    col0 = (xcd + ((slot & 3) << 3)) * 128;  // 32 col strips, strip%8 == xcd
    row0 = (slot >> 2) * 64;                 // 8 row blocks
    kbeg = 0;
  } else {
    col0 = xcd * 128;                        // 8 col blocks == 8 XCDs
    const int kz = slot & 3;                 // split-K slice
    row0 = (slot >> 2) * 64;                 // 8 row blocks
    kbeg = kz * KCH;
    outFb = outF + (size_t)kz * (NB * NH);
  }

  f32x4 acc[2][4] = {};

  // One staging group = 12 global_load_lds: A 4 rounds + B 8 rounds (16 rows,
  // 256 B each).
  auto stage = [&](int buf, int kt) {
#pragma unroll
    for (int i = 0; i < 4; ++i) {
      const bf16* ga = A + (size_t)(row0 + i * 16 + srow) * KST + kt + scol;
      __builtin_amdgcn_global_load_lds(
          (const __attribute__((address_space(1))) void*)ga,
          (__attribute__((address_space(3))) void*)(AsB + buf * 16384 + i * 4096 + tid * 16),
          16, 0, 0);
    }
#pragma unroll
    for (int i = 0; i < 8; ++i) {
      const bf16* gb = BT + (size_t)(col0 + i * 16 + srow) * KST + kt + scol;
      __builtin_amdgcn_global_load_lds(
          (const __attribute__((address_space(1))) void*)gb,
          (__attribute__((address_space(3))) void*)(BsB + buf * 32768 + i * 4096 + tid * 16),
          16, 0, 0);
    }
  };

  // Prologue: group 0 in flight.
  stage(0, kbeg);

#pragma unroll 1
  for (int j = 0; j < NI; ++j) {
    __builtin_amdgcn_s_barrier();      // all waves done reading buf (j&1)^1
    __builtin_amdgcn_sched_barrier(0);
    if (j + 1 < NI) stage((j + 1) & 1, kbeg + (j + 1) * BK);
    // Wait for group j; leave group j+1's 12 loads in flight.
    if (j + 1 < NI) asm volatile("s_waitcnt vmcnt(12)" ::: "memory");
    else            asm volatile("s_waitcnt vmcnt(0)" ::: "memory");
    __builtin_amdgcn_sched_barrier(0);

    const char* Ab = AsB + (j & 1) * 16384;
    const char* Bb = BsB + (j & 1) * 32768;
#pragma unroll
    for (int ks = 0; ks < BK; ks += 32) {
      const int kb2 = (ks + kg * 8) * 2;
      bf16x8 af[2], bf_[4];
#pragma unroll
      for (int mi = 0; mi < 2; ++mi) {
        const int r = wr * 32 + mi * 16 + l15;
        af[mi] = *reinterpret_cast<const bf16x8*>(Ab + ((r * 256 + kb2) ^ xorB));
      }
#pragma unroll
      for (int ni = 0; ni < 4; ++ni) {
        const int r = wc * 64 + ni * 16 + l15;
        bf_[ni] = *reinterpret_cast<const bf16x8*>(Bb + ((r * 256 + kb2) ^ xorB));
      }
#pragma unroll
      for (int mi = 0; mi < 2; ++mi)
#pragma unroll
        for (int ni = 0; ni < 4; ++ni)
          acc[mi][ni] = __builtin_amdgcn_mfma_f32_16x16x32_bf16(
              af[mi], bf_[ni], acc[mi][ni], 0, 0, 0);
    }
  }

  // Epilogue.  C/D layout: col = lane&15, row = (lane>>4)*4 + reg
#pragma unroll
  for (int mi = 0; mi < 2; ++mi) {
    const int gr0 = row0 + wr * 32 + mi * 16 + kg * 4;
#pragma unroll
    for (int ni = 0; ni < 4; ++ni) {
      const int gcol = col0 + wc * 64 + ni * 16 + l15;
      float b = 0.0f;
      if constexpr (EPI == 0) b = bias[gcol];
#pragma unroll
      for (int j = 0; j < 4; ++j) {
        const int r = gr0 + j;
        if constexpr (EPI == 0) {
          outB[(size_t)r * NOUT + (gcol ^ ((r & 7) << 3))] =
              __float2bfloat16(tanhf(acc[mi][ni][j] + b));
        } else {
          outFb[(size_t)r * NOUT + gcol] = acc[mi][ni][j];
        }
      }
    }
  }
}

// ---------------------------------------------------------------------------
// Combine split-K partials + RK4 (3/8 rule) stage algebra.
// k_s = sum(part) + b2; yb (and pred at s=4) stored chunk-swizzled.
// ---------------------------------------------------------------------------
__global__ void combine_stage(const float* __restrict__ part,
                              const float* __restrict__ b2,
                              float* __restrict__ y, bf16* __restrict__ yb,
                              float* __restrict__ k1, float* __restrict__ k2,
                              float* __restrict__ k3, bf16* __restrict__ pred_next,
                              const float* __restrict__ ts, int t, int s) {
  const int i = blockIdx.x * 256 + threadIdx.x;  // f32x4 index
  const float dt = ts[t + 1] - ts[t];
  constexpr int NE = NB * NH;

  f32x4 sum = {};
#pragma unroll
  for (int z = 0; z < SPLITK; ++z)
    sum += *reinterpret_cast<const f32x4*>(part + (size_t)z * NE + (size_t)i * 4);

  const int col = (i * 4) & (NH - 1);
  const int row = (i * 4) >> 10;
  const f32x4 bb = *reinterpret_cast<const f32x4*>(b2 + col);
  const f32x4 ksv = sum + bb;
  const f32x4 yv = *reinterpret_cast<const f32x4*>(y + (size_t)i * 4);

  f32x4 ynext;
  if (s == 1) {
    *reinterpret_cast<f32x4*>(k1 + (size_t)i * 4) = ksv;
    ynext = yv + ksv * (dt / 3.0f);
  } else if (s == 2) {
    const f32x4 k1v = *reinterpret_cast<const f32x4*>(k1 + (size_t)i * 4);
    *reinterpret_cast<f32x4*>(k2 + (size_t)i * 4) = ksv;
    ynext = yv + (ksv - k1v * (1.0f / 3.0f)) * dt;
  } else if (s == 3) {
    const f32x4 k1v = *reinterpret_cast<const f32x4*>(k1 + (size_t)i * 4);
    const f32x4 k2v = *reinterpret_cast<const f32x4*>(k2 + (size_t)i * 4);
    *reinterpret_cast<f32x4*>(k3 + (size_t)i * 4) = ksv;
    ynext = yv + (k1v - k2v + ksv) * dt;
  } else {
    const f32x4 k1v = *reinterpret_cast<const f32x4*>(k1 + (size_t)i * 4);
    const f32x4 k2v = *reinterpret_cast<const f32x4*>(k2 + (size_t)i * 4);
    const f32x4 k3v = *reinterpret_cast<const f32x4*>(k3 + (size_t)i * 4);
    ynext = yv + (k1v + (k2v + k3v) * 3.0f + ksv) * (dt * 0.125f);
    *reinterpret_cast<f32x4*>(y + (size_t)i * 4) = ynext;
  }

  union { bf16 h[4]; unsigned long long u; } pk;
#pragma unroll
  for (int j = 0; j < 4; ++j) pk.h[j] = __float2bfloat16(ynext[j]);
  const size_t sw = (size_t)row * NH + (col ^ ((row & 7) << 3));
  *reinterpret_cast<unsigned long long*>(yb + sw) = pk.u;
  if (s == 4) *reinterpret_cast<unsigned long long*>(pred_next + sw) = pk.u;
}

// ---------------------------------------------------------------------------
// Final projection GEMM: 128x128 tile, BK=64, depth-1 dbuf (proven round 7).
// ---------------------------------------------------------------------------
__global__ __launch_bounds__(256, 1) void proj_gemm(
    const bf16* __restrict__ A, const bf16* __restrict__ BT,
    int M, int N, int K, const float* __restrict__ bias,
    float* __restrict__ outF) {
  __shared__ __align__(16) bf16 As[2][128 * 64];
  __shared__ __align__(16) bf16 Bs[2][128 * 64];

  const int tid = threadIdx.x;
  const int lane = tid & 63;
  const int wave = tid >> 6;
  const int wr = wave >> 1, wc = wave & 1;
  const int row0 = blockIdx.y * 128, col0 = blockIdx.x * 128;
  const int l15 = lane & 15, kg = lane >> 4;
  const int xorB = (l15 & 7) << 4;
  const int srow = tid >> 3;
  const int scol = (tid & 7) * 8;

  f32x4 acc[4][4] = {};

  auto stage = [&](int buf, int kt) {
#pragma unroll
    for (int i = 0; i < 4; ++i) {
      const bf16* ga = A + (size_t)(row0 + i * 32 + srow) * K + kt + scol;
      __builtin_amdgcn_global_load_lds(
          (const __attribute__((address_space(1))) void*)ga,
          (__attribute__((address_space(3))) void*)&As[buf][i * 2048 + tid * 8],
          16, 0, 0);
      const bf16* gb = BT + (size_t)(col0 + i * 32 + srow) * K + kt + scol;
      __builtin_amdgcn_global_load_lds(
          (const __attribute__((address_space(1))) void*)gb,
          (__attribute__((address_space(3))) void*)&Bs[buf][i * 2048 + tid * 8],
          16, 0, 0);
    }
  };

  stage(0, 0);
  __syncthreads();
  int cur = 0;

  for (int kt = 0; kt < K; kt += 64) {
    if (kt + 64 < K) stage(cur ^ 1, kt + 64);
#pragma unroll
    for (int ks = 0; ks < 64; ks += 32) {
      const int kb2 = (ks + kg * 8) * 2;
      bf16x8 af[4], bf_[4];
#pragma unroll
      for (int mi = 0; mi < 4; ++mi) {
        const int r = wr * 64 + mi * 16 + l15;
        af[mi] = *reinterpret_cast<const bf16x8*>(
            (const char*)&As[cur][0] + ((r * 128 + kb2) ^ xorB));
      }
#pragma unroll
      for (int ni = 0; ni < 4; ++ni) {
        const int r = wc * 64 + ni * 16 + l15;
        bf_[ni] = *reinterpret_cast<const bf16x8*>(
            (const char*)&Bs[cur][0] + ((r * 128 + kb2) ^ xorB));
      }
#pragma unroll
      for (int mi = 0; mi < 4; ++mi)
#pragma unroll
        for (int ni = 0; ni < 4; ++ni)
          acc[mi][ni] = __builtin_amdgcn_mfma_f32_16x16x32_bf16(
              af[mi], bf_[ni], acc[mi][ni], 0, 0, 0);
    }
    __syncthreads();
    cur ^= 1;
  }

#pragma unroll
  for (int mi = 0; mi < 4; ++mi) {
    const int gr0 = row0 + wr * 64 + mi * 16 + kg * 4;
#pragma unroll
    for (int ni = 0; ni < 4; ++ni) {
      const int gcol = col0 + wc * 64 + ni * 16 + l15;
      const float b = bias[gcol];
#pragma unroll
      for (int j = 0; j < 4; ++j)
        outF[(size_t)(gr0 + j) * N + gcol] = acc[mi][ni][j] + b;
    }
  }
}

// ---------------------------------------------------------------------------
// In-place row softmax over C=512; one wave per row.
// ---------------------------------------------------------------------------
__global__ void softmax_rows(float* __restrict__ out) {
  const int row = blockIdx.x * 4 + (threadIdx.x >> 6);
  const int lane = threadIdx.x & 63;
  float* p = out + (size_t)row * NC + lane * 8;
  f32x4 a = *reinterpret_cast<const f32x4*>(p);
  f32x4 b = *reinterpret_cast<const f32x4*>(p + 4);

  float m = fmaxf(fmaxf(fmaxf(a[0], a[1]), fmaxf(a[2], a[3])),
                  fmaxf(fmaxf(b[0], b[1]), fmaxf(b[2], b[3])));
#pragma unroll
  for (int off = 32; off > 0; off >>= 1) m = fmaxf(m, __shfl_xor(m, off));

  f32x4 ea, eb;
  float sum = 0.0f;
#pragma unroll
  for (int j = 0; j < 4; ++j) { ea[j] = expf(a[j] - m); sum += ea[j]; }
#pragma unroll
  for (int j = 0; j < 4; ++j) { eb[j] = expf(b[j] - m); sum += eb[j]; }
#pragma unroll
  for (int off = 32; off > 0; off >>= 1) sum += __shfl_xor(sum, off);

  const float inv = 1.0f / sum;
  ea *= inv;
  eb *= inv;
  *reinterpret_cast<f32x4*>(p) = ea;
  *reinterpret_cast<f32x4*>(p + 4) = eb;
}

// ---------------------------------------------------------------------------
extern "C" void kernel_launch(void* const* d_in, const int* in_sizes, int n_in,
                              void* d_out, int out_size, void* d_ws, size_t ws_size,
                              hipStream_t stream) {
  const float* z = (const float*)d_in[0];
  const float* ts = (const float*)d_in[1];
  const float* W1 = (const float*)d_in[2];
  const float* b1 = (const float*)d_in[3];
  const float* W2 = (const float*)d_in[4];
  const float* b2 = (const float*)d_in[5];
  const float* Wf = (const float*)d_in[6];
  const float* bfv = (const float*)d_in[7];

  char* w = (char*)d_ws;
  bf16* W1bT = (bf16*)w;          w += (size_t)NOH * NH * 2;          // 8 MB
  bf16* W2bT = (bf16*)w;          w += (size_t)NH * NOH * 2;          // 8 MB
  bf16* WfT  = (bf16*)w;          w += (size_t)NC * NH * 2;           // 1 MB
  float* y   = (float*)w;         w += (size_t)NB * NH * 4;           // 2 MB
  bf16* yb   = (bf16*)w;          w += (size_t)NB * NH * 2;           // 1 MB
  float* k1  = (float*)w;         w += (size_t)NB * NH * 4;
  float* k2  = (float*)w;         w += (size_t)NB * NH * 4;
  float* k3  = (float*)w;         w += (size_t)NB * NH * 4;           // 6 MB
  bf16* h    = (bf16*)w;          w += (size_t)NB * NOH * 2;          // 4 MB
  float* part = (float*)w;        w += (size_t)SPLITK * NB * NH * 4;  // 8 MB
  bf16* pred = (bf16*)w;          w += (size_t)NT * NB * NH * 2;      // 40 MB

  float* logits = (float*)d_out;  // [NT*NB, NC] fp32, softmaxed in place

  // Weight transpose-casts (chunk-swizzled) + state init (stateless)
  transpose_cast<<<dim3(NOH / 32, NH / 32), dim3(32, 8), 0, stream>>>(W1, W1bT, NH, NOH);
  transpose_cast<<<dim3(NH / 32, NOH / 32), dim3(32, 8), 0, stream>>>(W2, W2bT, NOH, NH);
  transpose_cast<<<dim3(NC / 32, NH / 32), dim3(32, 8), 0, stream>>>(Wf, WfT, NH, NC);
  init_state<<<(NB * NH) / 256, 256, 0, stream>>>(z, y, yb, pred);

  hipFuncSetAttribute((const void*)gemm_stage<0>,
                      hipFuncAttributeMaxDynamicSharedMemorySize, 98304);
  hipFuncSetAttribute((const void*)gemm_stage<1>,
                      hipFuncAttributeMaxDynamicSharedMemorySize, 98304);

  for (int t = 0; t < NT - 1; ++t) {
    for (int s = 1; s <= 4; ++s) {
      // GEMM1: h = tanh(yb @ W1 + b1)  [512x4096], 256 WGs, 64x128 tiles
      gemm_stage<0><<<256, 256, 98304, stream>>>(yb, W1bT, b1, h, nullptr);
      // GEMM2: part[kz] = (h @ W2) K-chunks  [4 x 512x1024], 256 WGs
      gemm_stage<1><<<256, 256, 98304, stream>>>(h, W2bT, nullptr, nullptr, part);
      // combine + RK4 stage algebra
      combine_stage<<<512, 256, 0, stream>>>(
          part, b2, y, yb, k1, k2, k3, pred + (size_t)(t + 1) * NB * NH, ts, t, s);
    }
  }

  // logits = pred @ Wf + bf   [20480 x 512], then softmax
  proj_gemm<<<dim3(NC / 128, (NT * NB) / 128), 256, 0, stream>>>(
      pred, WfT, NT * NB, NC, NH, bfv, logits);
  softmax_rows<<<(NT * NB) / 4, 256, 0, stream>>>(logits);
}

// Round 16
// 4260.693 us; speedup vs baseline: 1.0238x; 1.0238x over previous
//
#include <hip/hip_runtime.h>
#include <hip/hip_bf16.h>
#include <math.h>

using bf16 = __hip_bfloat16;
typedef __bf16 bf16x8 __attribute__((ext_vector_type(8)));
typedef float f32x4 __attribute__((ext_vector_type(4)));

// Problem dims
static constexpr int NB = 512, NH = 1024, NOH = 4096, NC = 512, NT = 40;
static constexpr int SPLITK = 4;

// All LDS-staged matrices are "chunk-swizzled": element (r,k) stored at
// r*K + (k ^ ((r&7)<<3)) (within each 64-elem k-window).  global_load_lds
// copies rows linearly (swizzle-preserving); fragment reads XOR the byte
// address with ((l15&7)<<4), spreading 16 fragment rows over 8 bank groups.

// ---------------------------------------------------------------------------
// Transpose-cast fp32 (K x N) -> bf16 (N x K), chunk-swizzled.
// ---------------------------------------------------------------------------
__global__ void transpose_cast(const float* __restrict__ W, bf16* __restrict__ WT,
                               int K, int N) {
  __shared__ float tile[32][33];
  const int n0 = blockIdx.x * 32;
  const int k0 = blockIdx.y * 32;
  const int tx = threadIdx.x;
  const int ty = threadIdx.y;
#pragma unroll
  for (int i = 0; i < 4; ++i) {
    int r = ty + i * 8;
    tile[r][tx] = W[(size_t)(k0 + r) * N + n0 + tx];
  }
  __syncthreads();
#pragma unroll
  for (int i = 0; i < 4; ++i) {
    int r = ty + i * 8;
    const int n = n0 + r, k = k0 + tx;
    WT[(size_t)n * K + (k ^ ((n & 7) << 3))] = __float2bfloat16(tile[tx][r]);
  }
}

// ---------------------------------------------------------------------------
// Init: y = z (fp32), yb = pred[0] = bf16(z) (chunk-swizzled).
// ---------------------------------------------------------------------------
__global__ void init_state(const float* __restrict__ z, float* __restrict__ y,
                           bf16* __restrict__ yb, bf16* __restrict__ pred0) {
  const int i = blockIdx.x * 256 + threadIdx.x;
  const int r = i >> 10, c = i & (NH - 1);
  float v = z[i];
  y[i] = v;
  bf16 b = __float2bfloat16(v);
  const int sw = r * NH + (c ^ ((r & 7) << 3));
  yb[sw] = b;
  pred0[sw] = b;
}

// ---------------------------------------------------------------------------
// Stage GEMM: 64x64 tile, BK=128, K-chunk=1024 (8 iters), 4 waves (2x2).
// 2 LDS buffers (64 KB -> 2 blocks/CU), counted-vmcnt pipeline.  Per iter:
//   s_barrier                      (all waves done reading the other buffer)
//   issue group j+1 (8 loads)      (into the just-freed buffer)
//   s_waitcnt vmcnt(8)             (group j complete; group j+1 in flight)
//   compute buf j (16 MFMA/wave)
// XCD-aware decode: xcd = bid&7 -> weight strips stay in one XCD's L2.
// EPI 0 (GEMM1): h = bf16(tanh(acc + b1[col]))   [512x4096], swizzled store
// EPI 1 (GEMM2): part[kz] = acc (fp32 partials)  [4 x 512x1024]
// ---------------------------------------------------------------------------
template <int EPI>
__global__ __launch_bounds__(256, 2) void gemm_stage(
    const bf16* __restrict__ A, const bf16* __restrict__ BT,
    const float* __restrict__ bias, bf16* __restrict__ outB,
    float* __restrict__ outF) {
  constexpr int BK = 128;
  constexpr int KCH = 1024;
  constexpr int KST = (EPI == 0) ? NH : NOH;   // operand row stride
  constexpr int NOUT = (EPI == 0) ? NOH : NH;  // output row stride
  constexpr int NI = KCH / BK;                 // 8 K-iterations

  __shared__ __align__(16) bf16 As[2][64 * BK];  // 32 KB
  __shared__ __align__(16) bf16 Bs[2][64 * BK];  // 32 KB

  const int tid = threadIdx.x;
  const int lane = tid & 63;
  const int wave = tid >> 6;
  const int wr = wave >> 1, wc = wave & 1;
  const int l15 = lane & 15, kg = lane >> 4;
  const int xorB = (l15 & 7) << 4;
  const int srow = tid >> 4;        // staging row within 16-row round
  const int scol = (tid & 15) * 8;  // staging elem offset (128-elem rows)

  // XCD-aware task decode (blockIdx % 8 -> XCD round-robin)
  const int bid = blockIdx.x;
  const int xcd = bid & 7, slot = bid >> 3;
  int row0, col0, kbeg;
  float* outFb = outF;
  if constexpr (EPI == 0) {
    col0 = (xcd + ((slot & 7) << 3)) * 64;  // 64 col strips, strip%8 == xcd
    row0 = (slot >> 3) * 64;                // 8 row blocks
    kbeg = 0;
  } else {
    col0 = (xcd + ((slot & 1) << 3)) * 64;  // 16 col strips, strip%8 == xcd
    const int kz = (slot >> 1) & 3;         // split-K slice
    row0 = (slot >> 3) * 64;                // 8 row blocks
    kbeg = kz * KCH;
    outFb = outF + (size_t)kz * (NB * NH);
  }

  f32x4 acc[2][2] = {};

  // One staging group = 8 global_load_lds (4 rounds x {A,B}, 16 rows/round).
  auto stage = [&](int buf, int kt) {
#pragma unroll
    for (int i = 0; i < 4; ++i) {
      const bf16* ga = A + (size_t)(row0 + i * 16 + srow) * KST + kt + scol;
      __builtin_amdgcn_global_load_lds(
          (const __attribute__((address_space(1))) void*)ga,
          (__attribute__((address_space(3))) void*)&As[buf][i * 2048 + tid * 8],
          16, 0, 0);
      const bf16* gb = BT + (size_t)(col0 + i * 16 + srow) * KST + kt + scol;
      __builtin_amdgcn_global_load_lds(
          (const __attribute__((address_space(1))) void*)gb,
          (__attribute__((address_space(3))) void*)&Bs[buf][i * 2048 + tid * 8],
          16, 0, 0);
    }
  };

  // Prologue: group 0 in flight.
  stage(0, kbeg);

#pragma unroll 1
  for (int j = 0; j < NI; ++j) {
    __builtin_amdgcn_s_barrier();        // all waves done reading buf (j&1)^1
    __builtin_amdgcn_sched_barrier(0);
    if (j + 1 < NI) stage((j + 1) & 1, kbeg + (j + 1) * BK);
    // Wait for group j (leave group j+1's 8 loads in flight).
    if (j + 1 < NI) asm volatile("s_waitcnt vmcnt(8)" ::: "memory");
    else            asm volatile("s_waitcnt vmcnt(0)" ::: "memory");
    __builtin_amdgcn_sched_barrier(0);

    const char* Ab = (const char*)&As[j & 1][0];
    const char* Bb = (const char*)&Bs[j & 1][0];
#pragma unroll
    for (int ks = 0; ks < BK; ks += 32) {
      const int kb2 = (ks + kg * 8) * 2;
      bf16x8 af[2], bf_[2];
#pragma unroll
      for (int mi = 0; mi < 2; ++mi) {
        const int r = wr * 32 + mi * 16 + l15;
        af[mi] = *reinterpret_cast<const bf16x8*>(Ab + ((r * 256 + kb2) ^ xorB));
      }
#pragma unroll
      for (int ni = 0; ni < 2; ++ni) {
        const int r = wc * 32 + ni * 16 + l15;
        bf_[ni] = *reinterpret_cast<const bf16x8*>(Bb + ((r * 256 + kb2) ^ xorB));
      }
#pragma unroll
      for (int mi = 0; mi < 2; ++mi)
#pragma unroll
        for (int ni = 0; ni < 2; ++ni)
          acc[mi][ni] = __builtin_amdgcn_mfma_f32_16x16x32_bf16(
              af[mi], bf_[ni], acc[mi][ni], 0, 0, 0);
    }
  }

  // Epilogue.  C/D layout: col = lane&15, row = (lane>>4)*4 + reg
#pragma unroll
  for (int mi = 0; mi < 2; ++mi) {
    const int gr0 = row0 + wr * 32 + mi * 16 + kg * 4;
#pragma unroll
    for (int ni = 0; ni < 2; ++ni) {
      const int gcol = col0 + wc * 32 + ni * 16 + l15;
      float b = 0.0f;
      if constexpr (EPI == 0) b = bias[gcol];
#pragma unroll
      for (int j = 0; j < 4; ++j) {
        const int r = gr0 + j;
        if constexpr (EPI == 0) {
          outB[(size_t)r * NOUT + (gcol ^ ((r & 7) << 3))] =
              __float2bfloat16(tanhf(acc[mi][ni][j] + b));
        } else {
          outFb[(size_t)r * NOUT + gcol] = acc[mi][ni][j];
        }
      }
    }
  }
}

// ---------------------------------------------------------------------------
// Combine split-K partials + RK4 (3/8 rule) stage algebra.
// k_s = sum(part) + b2; yb (and pred at s=4) stored chunk-swizzled.
// ---------------------------------------------------------------------------
__global__ void combine_stage(const float* __restrict__ part,
                              const float* __restrict__ b2,
                              float* __restrict__ y, bf16* __restrict__ yb,
                              float* __restrict__ k1, float* __restrict__ k2,
                              float* __restrict__ k3, bf16* __restrict__ pred_next,
                              const float* __restrict__ ts, int t, int s) {
  const int i = blockIdx.x * 256 + threadIdx.x;  // f32x4 index
  const float dt = ts[t + 1] - ts[t];
  constexpr int NE = NB * NH;

  f32x4 sum = {};
#pragma unroll
  for (int z = 0; z < SPLITK; ++z)
    sum += *reinterpret_cast<const f32x4*>(part + (size_t)z * NE + (size_t)i * 4);

  const int col = (i * 4) & (NH - 1);
  const int row = (i * 4) >> 10;
  const f32x4 bb = *reinterpret_cast<const f32x4*>(b2 + col);
  const f32x4 ksv = sum + bb;
  const f32x4 yv = *reinterpret_cast<const f32x4*>(y + (size_t)i * 4);

  f32x4 ynext;
  if (s == 1) {
    *reinterpret_cast<f32x4*>(k1 + (size_t)i * 4) = ksv;
    ynext = yv + ksv * (dt / 3.0f);
  } else if (s == 2) {
    const f32x4 k1v = *reinterpret_cast<const f32x4*>(k1 + (size_t)i * 4);
    *reinterpret_cast<f32x4*>(k2 + (size_t)i * 4) = ksv;
    ynext = yv + (ksv - k1v * (1.0f / 3.0f)) * dt;
  } else if (s == 3) {
    const f32x4 k1v = *reinterpret_cast<const f32x4*>(k1 + (size_t)i * 4);
    const f32x4 k2v = *reinterpret_cast<const f32x4*>(k2 + (size_t)i * 4);
    *reinterpret_cast<f32x4*>(k3 + (size_t)i * 4) = ksv;
    ynext = yv + (k1v - k2v + ksv) * dt;
  } else {
    const f32x4 k1v = *reinterpret_cast<const f32x4*>(k1 + (size_t)i * 4);
    const f32x4 k2v = *reinterpret_cast<const f32x4*>(k2 + (size_t)i * 4);
    const f32x4 k3v = *reinterpret_cast<const f32x4*>(k3 + (size_t)i * 4);
    ynext = yv + (k1v + (k2v + k3v) * 3.0f + ksv) * (dt * 0.125f);
    *reinterpret_cast<f32x4*>(y + (size_t)i * 4) = ynext;
  }

  union { bf16 h[4]; unsigned long long u; } pk;
#pragma unroll
  for (int j = 0; j < 4; ++j) pk.h[j] = __float2bfloat16(ynext[j]);
  const size_t sw = (size_t)row * NH + (col ^ ((row & 7) << 3));
  *reinterpret_cast<unsigned long long*>(yb + sw) = pk.u;
  if (s == 4) *reinterpret_cast<unsigned long long*>(pred_next + sw) = pk.u;
}

// ---------------------------------------------------------------------------
// Final projection GEMM: 128x128 tile, BK=64, depth-1 dbuf (proven round 7).
// ---------------------------------------------------------------------------
__global__ __launch_bounds__(256, 1) void proj_gemm(
    const bf16* __restrict__ A, const bf16* __restrict__ BT,
    int M, int N, int K, const float* __restrict__ bias,
    float* __restrict__ outF) {
  __shared__ __align__(16) bf16 As[2][128 * 64];
  __shared__ __align__(16) bf16 Bs[2][128 * 64];

  const int tid = threadIdx.x;
  const int lane = tid & 63;
  const int wave = tid >> 6;
  const int wr = wave >> 1, wc = wave & 1;
  const int row0 = blockIdx.y * 128, col0 = blockIdx.x * 128;
  const int l15 = lane & 15, kg = lane >> 4;
  const int xorB = (l15 & 7) << 4;
  const int srow = tid >> 3;
  const int scol = (tid & 7) * 8;

  f32x4 acc[4][4] = {};

  auto stage = [&](int buf, int kt) {
#pragma unroll
    for (int i = 0; i < 4; ++i) {
      const bf16* ga = A + (size_t)(row0 + i * 32 + srow) * K + kt + scol;
      __builtin_amdgcn_global_load_lds(
          (const __attribute__((address_space(1))) void*)ga,
          (__attribute__((address_space(3))) void*)&As[buf][i * 2048 + tid * 8],
          16, 0, 0);
      const bf16* gb = BT + (size_t)(col0 + i * 32 + srow) * K + kt + scol;
      __builtin_amdgcn_global_load_lds(
          (const __attribute__((address_space(1))) void*)gb,
          (__attribute__((address_space(3))) void*)&Bs[buf][i * 2048 + tid * 8],
          16, 0, 0);
    }
  };

  stage(0, 0);
  __syncthreads();
  int cur = 0;

  for (int kt = 0; kt < K; kt += 64) {
    if (kt + 64 < K) stage(cur ^ 1, kt + 64);
#pragma unroll
    for (int ks = 0; ks < 64; ks += 32) {
      const int kb2 = (ks + kg * 8) * 2;
      bf16x8 af[4], bf_[4];
#pragma unroll
      for (int mi = 0; mi < 4; ++mi) {
        const int r = wr * 64 + mi * 16 + l15;
        af[mi] = *reinterpret_cast<const bf16x8*>(
            (const char*)&As[cur][0] + ((r * 128 + kb2) ^ xorB));
      }
#pragma unroll
      for (int ni = 0; ni < 4; ++ni) {
        const int r = wc * 64 + ni * 16 + l15;
        bf_[ni] = *reinterpret_cast<const bf16x8*>(
            (const char*)&Bs[cur][0] + ((r * 128 + kb2) ^ xorB));
      }
#pragma unroll
      for (int mi = 0; mi < 4; ++mi)
#pragma unroll
        for (int ni = 0; ni < 4; ++ni)
          acc[mi][ni] = __builtin_amdgcn_mfma_f32_16x16x32_bf16(
              af[mi], bf_[ni], acc[mi][ni], 0, 0, 0);
    }
    __syncthreads();
    cur ^= 1;
  }

#pragma unroll
  for (int mi = 0; mi < 4; ++mi) {
    const int gr0 = row0 + wr * 64 + mi * 16 + kg * 4;
#pragma unroll
    for (int ni = 0; ni < 4; ++ni) {
      const int gcol = col0 + wc * 64 + ni * 16 + l15;
      const float b = bias[gcol];
#pragma unroll
      for (int j = 0; j < 4; ++j)
        outF[(size_t)(gr0 + j) * N + gcol] = acc[mi][ni][j] + b;
    }
  }
}

// ---------------------------------------------------------------------------
// In-place row softmax over C=512; one wave per row.
// ---------------------------------------------------------------------------
__global__ void softmax_rows(float* __restrict__ out) {
  const int row = blockIdx.x * 4 + (threadIdx.x >> 6);
  const int lane = threadIdx.x & 63;
  float* p = out + (size_t)row * NC + lane * 8;
  f32x4 a = *reinterpret_cast<const f32x4*>(p);
  f32x4 b = *reinterpret_cast<const f32x4*>(p + 4);

  float m = fmaxf(fmaxf(fmaxf(a[0], a[1]), fmaxf(a[2], a[3])),
                  fmaxf(fmaxf(b[0], b[1]), fmaxf(b[2], b[3])));
#pragma unroll
  for (int off = 32; off > 0; off >>= 1) m = fmaxf(m, __shfl_xor(m, off));

  f32x4 ea, eb;
  float sum = 0.0f;
#pragma unroll
  for (int j = 0; j < 4; ++j) { ea[j] = expf(a[j] - m); sum += ea[j]; }
#pragma unroll
  for (int j = 0; j < 4; ++j) { eb[j] = expf(b[j] - m); sum += eb[j]; }
#pragma unroll
  for (int off = 32; off > 0; off >>= 1) sum += __shfl_xor(sum, off);

  const float inv = 1.0f / sum;
  ea *= inv;
  eb *= inv;
  *reinterpret_cast<f32x4*>(p) = ea;
  *reinterpret_cast<f32x4*>(p + 4) = eb;
}

// ---------------------------------------------------------------------------
extern "C" void kernel_launch(void* const* d_in, const int* in_sizes, int n_in,
                              void* d_out, int out_size, void* d_ws, size_t ws_size,
                              hipStream_t stream) {
  const float* z = (const float*)d_in[0];
  const float* ts = (const float*)d_in[1];
  const float* W1 = (const float*)d_in[2];
  const float* b1 = (const float*)d_in[3];
  const float* W2 = (const float*)d_in[4];
  const float* b2 = (const float*)d_in[5];
  const float* Wf = (const float*)d_in[6];
  const float* bfv = (const float*)d_in[7];

  char* w = (char*)d_ws;
  bf16* W1bT = (bf16*)w;          w += (size_t)NOH * NH * 2;          // 8 MB
  bf16* W2bT = (bf16*)w;          w += (size_t)NH * NOH * 2;          // 8 MB
  bf16* WfT  = (bf16*)w;          w += (size_t)NC * NH * 2;           // 1 MB
  float* y   = (float*)w;         w += (size_t)NB * NH * 4;           // 2 MB
  bf16* yb   = (bf16*)w;          w += (size_t)NB * NH * 2;           // 1 MB
  float* k1  = (float*)w;         w += (size_t)NB * NH * 4;
  float* k2  = (float*)w;         w += (size_t)NB * NH * 4;
  float* k3  = (float*)w;         w += (size_t)NB * NH * 4;           // 6 MB
  bf16* h    = (bf16*)w;          w += (size_t)NB * NOH * 2;          // 4 MB
  float* part = (float*)w;        w += (size_t)SPLITK * NB * NH * 4;  // 8 MB
  bf16* pred = (bf16*)w;          w += (size_t)NT * NB * NH * 2;      // 40 MB

  float* logits = (float*)d_out;  // [NT*NB, NC] fp32, softmaxed in place

  // Weight transpose-casts (chunk-swizzled) + state init (stateless)
  transpose_cast<<<dim3(NOH / 32, NH / 32), dim3(32, 8), 0, stream>>>(W1, W1bT, NH, NOH);
  transpose_cast<<<dim3(NH / 32, NOH / 32), dim3(32, 8), 0, stream>>>(W2, W2bT, NOH, NH);
  transpose_cast<<<dim3(NC / 32, NH / 32), dim3(32, 8), 0, stream>>>(Wf, WfT, NH, NC);
  init_state<<<(NB * NH) / 256, 256, 0, stream>>>(z, y, yb, pred);

  for (int t = 0; t < NT - 1; ++t) {
    for (int s = 1; s <= 4; ++s) {
      // GEMM1: h = tanh(yb @ W1 + b1)  [512x4096], 512 WGs, XCD-partitioned
      gemm_stage<0><<<512, 256, 0, stream>>>(yb, W1bT, b1, h, nullptr);
      // GEMM2: part[kz] = (h @ W2) K-chunks  [4 x 512x1024], 512 WGs
      gemm_stage<1><<<512, 256, 0, stream>>>(h, W2bT, nullptr, nullptr, part);
      // combine + RK4 stage algebra
      combine_stage<<<512, 256, 0, stream>>>(
          part, b2, y, yb, k1, k2, k3, pred + (size_t)(t + 1) * NB * NH, ts, t, s);
    }
  }

  // logits = pred @ Wf + bf   [20480 x 512], then softmax
  proj_gemm<<<dim3(NC / 128, (NT * NB) / 128), 256, 0, stream>>>(
      pred, WfT, NT * NB, NC, NH, bfv, logits);
  softmax_rows<<<(NT * NB) / 4, 256, 0, stream>>>(logits);
}